// Round 2
// baseline (389.808 us; speedup 1.0000x reference)
//
#include <hip/hip_runtime.h>
#include <math.h>

#define D 128
#define B_SZ 1024
#define KNB 200
#define AHW 392   // [q|h|r] LDS stride (halves): 196 dw, %32=4 -> cheap 2-way pairs
#define PW 1048   // P LDS stride (halves)

typedef _Float16 half8 __attribute__((ext_vector_type(8)));
typedef float floatx4 __attribute__((ext_vector_type(4)));

__device__ __forceinline__ float sigmoid_f(float x) { return 1.f / (1.f + __expf(-x)); }
__device__ __forceinline__ float tanh_fast(float x) { return 1.f - 2.f / (__expf(2.f * x) + 1.f); }

// ---------------------------------------------------------------------------
// Kernel 0: one-time fp16 LSTM weights (split layout):
// w16[0:131072] = w_ih [1024][128]; w16[131072:] = w_hh [1024][256].
// ---------------------------------------------------------------------------
__global__ __launch_bounds__(256) void k_cvtw(
    const float* __restrict__ w_ih, const float* __restrict__ w_hh,
    _Float16* __restrict__ w16)
{
    const int i8 = (blockIdx.x * 256 + threadIdx.x) * 8;
    const float* src = (i8 < 131072) ? (w_ih + i8) : (w_hh + (i8 - 131072));
    float4 v0 = *(const float4*)src;
    float4 v1 = *(const float4*)(src + 4);
    half8 h;
    h[0] = (_Float16)v0.x; h[1] = (_Float16)v0.y; h[2] = (_Float16)v0.z; h[3] = (_Float16)v0.w;
    h[4] = (_Float16)v1.x; h[5] = (_Float16)v1.y; h[6] = (_Float16)v1.z; h[7] = (_Float16)v1.w;
    *(half8*)&w16[i8] = h;
}

// ---------------------------------------------------------------------------
// Kernel 1: gather+sum, GCN linear, support encoder, query gather.
// One block per batch row b, 512 threads. (Known wall: ~1.25 TB/s random.)
// ---------------------------------------------------------------------------
__global__ __launch_bounds__(512) void k_support(
    const int* __restrict__ relations, const int* __restrict__ entities,
    const int* __restrict__ query, const float* __restrict__ emb,
    const float* __restrict__ gcn_w, const float* __restrict__ gcn_b,
    const float* __restrict__ p1_w, const float* __restrict__ p1_b,
    const float* __restrict__ p2_w, const float* __restrict__ p2_b,
    const float* __restrict__ ln_a, const float* __restrict__ ln_b,
    float* __restrict__ sg, _Float16* __restrict__ sgH, _Float16* __restrict__ sgT,
    float* __restrict__ qb, _Float16* __restrict__ qbH)
{
    __shared__ int idxs[2 * KNB];
    __shared__ __align__(16) float part[16][132];
    __shared__ __align__(16) float S[2 * D];
    __shared__ __align__(16) float sup[D];
    __shared__ __align__(16) float hid[2 * D];
    __shared__ __align__(16) float zv[D];
    __shared__ float red2[2];

    const int b = blockIdx.x;
    const int t = threadIdx.x;

    if (t < KNB) idxs[t] = relations[b * KNB + t];
    else if (t < 2 * KNB) idxs[t] = entities[b * KNB + (t - KNB)];
    __syncthreads();

    {
        const int g = t >> 5, c4 = (t & 31) * 4;
        const int* mi = &idxs[(g >> 3) * KNB];
        float4 a4 = make_float4(0.f, 0.f, 0.f, 0.f);
        #pragma unroll 5
        for (int k = (g & 7); k < KNB; k += 8) {
            float4 v = *(const float4*)&emb[(size_t)mi[k] * D + c4];
            a4.x += v.x; a4.y += v.y; a4.z += v.z; a4.w += v.w;
        }
        *(float4*)&part[g][c4] = a4;
    }
    __syncthreads();
    if (t < 2 * D) {
        const int half = t >> 7, c = t & 127;
        float s = 0.f;
        #pragma unroll
        for (int j = 0; j < 8; ++j) s += part[half * 8 + j][c];
        S[t] = s;
    }
    __syncthreads();

    if (t < D) {
        const float4* w4 = (const float4*)(gcn_w + t * 2 * D);
        float dot = 0.f;
        #pragma unroll 8
        for (int f = 0; f < 2 * D / 4; ++f) {
            float4 w = w4[f];
            float4 s = *(const float4*)&S[f * 4];
            dot += w.x * s.x + w.y * s.y + w.z * s.z + w.w * s.w;
        }
        float v = (dot + 200.f * gcn_b[t]) * (1.f / 1024.f);  // num_neighbors = B = 1024
        sup[t] = tanhf(v);
    }
    __syncthreads();

    if (t < 2 * D) {
        const float4* w4 = (const float4*)(p1_w + t * D);
        float dot = 0.f;
        #pragma unroll 8
        for (int f = 0; f < D / 4; ++f) {
            float4 w = w4[f];
            float4 s = *(const float4*)&sup[f * 4];
            dot += w.x * s.x + w.y * s.y + w.z * s.z + w.w * s.w;
        }
        float h = dot + p1_b[t];
        hid[t] = h > 0.f ? h : 0.f;
    }
    __syncthreads();

    if (t < D) {
        const float4* w4 = (const float4*)(p2_w + t * 2 * D);
        float dot = 0.f;
        #pragma unroll 8
        for (int f = 0; f < 2 * D / 4; ++f) {
            float4 w = w4[f];
            float4 s = *(const float4*)&hid[f * 4];
            dot += w.x * s.x + w.y * s.y + w.z * s.z + w.w * s.w;
        }
        zv[t] = dot + p2_b[t] + sup[t];
    }
    __syncthreads();

    if (t < 64) {
        float x0 = zv[t], x1 = zv[t + 64];
        float s = x0 + x1;
        for (int off = 32; off; off >>= 1) s += __shfl_down(s, off);
        float mu = __shfl(s, 0) * (1.f / 128.f);
        float d0 = x0 - mu, d1 = x1 - mu;
        float v = d0 * d0 + d1 * d1;
        for (int off = 32; off; off >>= 1) v += __shfl_down(v, off);
        v = __shfl(v, 0);
        if (t == 0) { red2[0] = mu; red2[1] = sqrtf(v * (1.f / 127.f)); }
    }
    __syncthreads();
    if (t < D) {
        float mu = red2[0], sigma = red2[1];
        float val = (zv[t] - mu) / (sigma + 1e-3f) * ln_a[t] + ln_b[t];
        sg[b * D + t] = val;
        sgH[b * D + t] = (_Float16)val;
        sgT[t * B_SZ + b] = (_Float16)val;
        float qv = emb[(size_t)query[b] * D + t];
        qb[b * D + t] = qv;
        qbH[b * D + t] = (_Float16)qv;
    }
}

// ---------------------------------------------------------------------------
// Kernel 2: FUSED recurrence, spill-free version. 64 blocks x 16 rows,
// 1024 threads (16 waves).
// gates = [q|h|r] @ [w_ih|w_hh]^T as ONE K=384 GEMM from the Ah LDS tile;
// q.w_ih recomputed each step (L2-resident weights) instead of 16 persistent
// VGPRs. Persistent per-thread state: creg[4] + bi[4] only -> no spill.
// ---------------------------------------------------------------------------
__global__ __launch_bounds__(1024) void k_lstm(
    const _Float16* __restrict__ qbH, const float* __restrict__ qb,
    const _Float16* __restrict__ sgH, const _Float16* __restrict__ sgT,
    const float* __restrict__ sg, const _Float16* __restrict__ w16,
    const float* __restrict__ b_ih, const float* __restrict__ b_hh,
    float* __restrict__ out)
{
    __shared__ _Float16 Ah[16 * AHW];      // [row][0:128]=q, [128:256]=h, [256:384]=r
    __shared__ _Float16 P[16 * PW];        // unnormalized exp, fp16
    __shared__ float qF[16][132];          // q f32 (pointwise residual)
    __shared__ float hF[16][132];          // h f32 (for cosine)
    __shared__ float rpar[2][16][132];     // r K-half partials
    __shared__ float pred[16][17];         // [wave][row] partial max / partial sum
    __shared__ float mrow[16];
    __shared__ float sinv[16];

    const int t = threadIdx.x;
    const int w = t >> 6, lane = t & 63;
    const int m = lane & 15, quad = lane >> 4;
    const int b0 = blockIdx.x * 16;
    const int u = w * 16 + m;              // unit 0..255

    // ---- prologue: stage q (f16 into Ah[:,0:128], f32 into qF); zero h|r
    if (t < 256) {
        const int row = t >> 4, c = (t & 15) * 8;
        *(half8*)&Ah[row * AHW + c] = *(const half8*)&qbH[(b0 + row) * D + c];
    }
    if (t < 512) {
        const int row = t >> 5, c = (t & 31) * 4;
        *(float4*)&qF[row][c] = *(const float4*)&qb[(b0 + row) * D + c];
    }
    if (t < 512) {   // zero Ah[:,128:384]: 16 rows x 256 halves = 512 half8
        const int row = t >> 5, c = (t & 31) * 8 + 128;
        half8 z;
        #pragma unroll
        for (int i = 0; i < 8; ++i) z[i] = (_Float16)0.f;
        *(half8*)&Ah[row * AHW + c] = z;
    }
    float bi[4];
    #pragma unroll
    for (int g = 0; g < 4; ++g) bi[g] = b_ih[g * 256 + u] + b_hh[g * 256 + u];
    float creg[4] = {0.f, 0.f, 0.f, 0.f};
    __syncthreads();

    #pragma unroll 1
    for (int s = 0; s < 4; ++s) {
        if (s > 0) {
            // ---- scores: wave w -> j-tiles 4w..4w+3 (h lives at Ah[:,128:256])
            floatx4 a2[4];
            #pragma unroll
            for (int i = 0; i < 4; ++i)
                #pragma unroll
                for (int z = 0; z < 4; ++z) a2[i][z] = 0.f;
            #pragma unroll
            for (int ks = 0; ks < 4; ++ks) {
                half8 a = *(const half8*)&Ah[m * AHW + 128 + ks * 32 + quad * 8];
                #pragma unroll
                for (int i = 0; i < 4; ++i) {
                    const int j0 = (w * 4 + i) * 16;
                    half8 bf = *(const half8*)&sgH[(j0 + m) * D + ks * 32 + quad * 8];
                    a2[i] = __builtin_amdgcn_mfma_f32_16x16x32_f16(a, bf, a2[i], 0, 0, 0);
                }
            }

            // ---- softmax (register partials + two small LDS reductions)
            float mloc[4];
            #pragma unroll
            for (int rr = 0; rr < 4; ++rr)
                mloc[rr] = fmaxf(fmaxf(a2[0][rr], a2[1][rr]), fmaxf(a2[2][rr], a2[3][rr]));
            #pragma unroll
            for (int off = 1; off <= 8; off <<= 1)
                #pragma unroll
                for (int rr = 0; rr < 4; ++rr)
                    mloc[rr] = fmaxf(mloc[rr], __shfl_xor(mloc[rr], off));
            if (m == 0) {
                #pragma unroll
                for (int rr = 0; rr < 4; ++rr) pred[w][quad * 4 + rr] = mloc[rr];
            }
            __syncthreads();
            if (t < 16) {
                float mm = -1e30f;
                #pragma unroll
                for (int ww = 0; ww < 16; ++ww) mm = fmaxf(mm, pred[ww][t]);
                mrow[t] = mm;
            }
            __syncthreads();

            float sloc[4] = {0.f, 0.f, 0.f, 0.f};
            #pragma unroll
            for (int i = 0; i < 4; ++i) {
                const int col = (w * 4 + i) * 16 + m;
                #pragma unroll
                for (int rr = 0; rr < 4; ++rr) {
                    const int row = quad * 4 + rr;
                    float e = __expf(a2[i][rr] - mrow[row]);
                    P[row * PW + col] = (_Float16)e;
                    sloc[rr] += e;
                }
            }
            #pragma unroll
            for (int off = 1; off <= 8; off <<= 1)
                #pragma unroll
                for (int rr = 0; rr < 4; ++rr)
                    sloc[rr] += __shfl_xor(sloc[rr], off);
            if (m == 0) {
                #pragma unroll
                for (int rr = 0; rr < 4; ++rr) pred[w][quad * 4 + rr] = sloc[rr];
            }
            __syncthreads();
            if (t < 16) {
                float ss = 0.f;
                #pragma unroll
                for (int ww = 0; ww < 16; ++ww) ss += pred[ww][t];
                sinv[t] = 1.f / ss;
            }

            // ---- r partials: wave -> (n-tile = w&7, K-half = w>>3)
            {
                const int nt = w & 7, kh = w >> 3;
                floatx4 a3;
                #pragma unroll
                for (int z = 0; z < 4; ++z) a3[z] = 0.f;
                #pragma unroll
                for (int ks = 0; ks < 16; ++ks) {
                    const int kk = kh * 16 + ks;
                    half8 a = *(const half8*)&P[m * PW + kk * 32 + quad * 8];
                    half8 bf = *(const half8*)&sgT[(nt * 16 + m) * B_SZ + kk * 32 + quad * 8];
                    a3 = __builtin_amdgcn_mfma_f32_16x16x32_f16(a, bf, a3, 0, 0, 0);
                }
                #pragma unroll
                for (int rr = 0; rr < 4; ++rr)
                    rpar[kh][quad * 4 + rr][nt * 16 + m] = a3[rr];
            }
            __syncthreads();

            // ---- combine + scale -> r fp16 into Ah[:,256:384]
            #pragma unroll
            for (int half2 = 0; half2 < 2; ++half2) {
                const int e = t + half2 * 1024;
                const int row = e >> 7, dd = e & 127;
                float v = (rpar[0][row][dd] + rpar[1][row][dd]) * sinv[row];
                Ah[row * AHW + 256 + dd] = (_Float16)v;
            }
            __syncthreads();
        }

        // ---- gates: acc = [q|h|r] @ [w_ih|w_hh]^T  (K = 384; h=r=0 at s=0)
        floatx4 acc[4];
        #pragma unroll
        for (int g = 0; g < 4; ++g)
            #pragma unroll
            for (int z = 0; z < 4; ++z) acc[g][z] = 0.f;
        #pragma unroll
        for (int ks = 0; ks < 12; ++ks) {
            half8 a = *(const half8*)&Ah[m * AHW + ks * 32 + quad * 8];
            #pragma unroll
            for (int g = 0; g < 4; ++g) {
                const int row = g * 256 + u;
                half8 bf;
                if (ks < 4)
                    bf = *(const half8*)&w16[(size_t)row * 128 + ks * 32 + quad * 8];
                else
                    bf = *(const half8*)&w16[131072 + (size_t)row * 256 + (ks - 4) * 32 + quad * 8];
                acc[g] = __builtin_amdgcn_mfma_f32_16x16x32_f16(a, bf, acc[g], 0, 0, 0);
            }
        }
        __syncthreads();   // all Ah reads done before h is overwritten

        // ---- pointwise
        #pragma unroll
        for (int rr = 0; rr < 4; ++rr) {
            float gi = acc[0][rr] + bi[0];
            float gf = acc[1][rr] + bi[1];
            float gg = acc[2][rr] + bi[2];
            float go = acc[3][rr] + bi[3];
            float cn = sigmoid_f(gf) * creg[rr] + sigmoid_f(gi) * tanh_fast(gg);
            creg[rr] = cn;
            if (w < 8) {
                const int row = quad * 4 + rr;
                float ho = qF[row][u] + sigmoid_f(go) * tanh_fast(cn);
                Ah[row * AHW + 128 + u] = (_Float16)ho;
                hF[row][u] = ho;
            }
        }
        __syncthreads();
    }

    // ---- cosine: wave w -> row w
    {
        const int row = w;
        float a0 = hF[row][lane], a1 = hF[row][lane + 64];
        float s0 = sg[(b0 + row) * D + lane], s1 = sg[(b0 + row) * D + lane + 64];
        float cr = a0 * s0 + a1 * s1;
        float n1 = a0 * a0 + a1 * a1;
        float n2 = s0 * s0 + s1 * s1;
        for (int off = 32; off; off >>= 1) {
            cr += __shfl_down(cr, off);
            n1 += __shfl_down(n1, off);
            n2 += __shfl_down(n2, off);
        }
        if (lane == 0) out[b0 + row] = cr / sqrtf(n1 * n2);
    }
}

// ---------------------------------------------------------------------------
extern "C" void kernel_launch(void* const* d_in, const int* in_sizes, int n_in,
                              void* d_out, int out_size, void* d_ws, size_t ws_size,
                              hipStream_t stream)
{
    const int*   relations = (const int*)d_in[0];
    const int*   entities  = (const int*)d_in[1];
    const int*   query     = (const int*)d_in[2];
    const float* emb       = (const float*)d_in[3];
    const float* gcn_w     = (const float*)d_in[4];
    const float* gcn_b     = (const float*)d_in[5];
    const float* p1_w      = (const float*)d_in[6];
    const float* p1_b      = (const float*)d_in[7];
    const float* p2_w      = (const float*)d_in[8];
    const float* p2_b      = (const float*)d_in[9];
    const float* ln_a      = (const float*)d_in[10];
    const float* ln_b      = (const float*)d_in[11];
    const float* w_ih      = (const float*)d_in[12];
    const float* w_hh      = (const float*)d_in[13];
    const float* b_ih      = (const float*)d_in[14];
    const float* b_hh      = (const float*)d_in[15];

    // Workspace layout (float-slot offsets)
    float* ws = (float*)d_ws;
    float*     sg   = ws;                          // 131072
    float*     qb   = ws + 131072;                 // 131072
    _Float16*  sgH  = (_Float16*)(ws + 262144);    // 65536 float slots
    _Float16*  sgT  = (_Float16*)(ws + 327680);
    _Float16*  qbH  = (_Float16*)(ws + 393216);
    _Float16*  w16  = (_Float16*)(ws + 458752);    // 196608 float slots
    // end: 655360 floats = 2.6 MB

    k_cvtw<<<dim3(192), dim3(256), 0, stream>>>(w_ih, w_hh, w16);
    k_support<<<dim3(B_SZ), dim3(512), 0, stream>>>(
        relations, entities, query, emb, gcn_w, gcn_b,
        p1_w, p1_b, p2_w, p2_b, ln_a, ln_b, sg, sgH, sgT, qb, qbH);
    k_lstm<<<dim3(64), dim3(1024), 0, stream>>>(
        qbH, qb, sgH, sgT, sg, w16, b_ih, b_hh, (float*)d_out);
}

// Round 3
// 374.056 us; speedup vs baseline: 1.0421x; 1.0421x over previous
//
#include <hip/hip_runtime.h>
#include <math.h>

#define D 128
#define B_SZ 1024
#define KNB 200
#define AHW 392   // [q|h|r] LDS stride (halves): 196 dw, %32=4 -> cheap 2-way pairs
#define PW 1048   // P LDS stride (halves)

typedef _Float16 half8 __attribute__((ext_vector_type(8)));
typedef float floatx4 __attribute__((ext_vector_type(4)));

__device__ __forceinline__ float sigmoid_f(float x) { return 1.f / (1.f + __expf(-x)); }
__device__ __forceinline__ float tanh_fast(float x) { return 1.f - 2.f / (__expf(2.f * x) + 1.f); }

// ---------------------------------------------------------------------------
// Kernel 0: one-time fp16 LSTM weights (split layout):
// w16[0:131072] = w_ih [1024][128]; w16[131072:] = w_hh [1024][256].
// ---------------------------------------------------------------------------
__global__ __launch_bounds__(256) void k_cvtw(
    const float* __restrict__ w_ih, const float* __restrict__ w_hh,
    _Float16* __restrict__ w16)
{
    const int i8 = (blockIdx.x * 256 + threadIdx.x) * 8;
    const float* src = (i8 < 131072) ? (w_ih + i8) : (w_hh + (i8 - 131072));
    float4 v0 = *(const float4*)src;
    float4 v1 = *(const float4*)(src + 4);
    half8 h;
    h[0] = (_Float16)v0.x; h[1] = (_Float16)v0.y; h[2] = (_Float16)v0.z; h[3] = (_Float16)v0.w;
    h[4] = (_Float16)v1.x; h[5] = (_Float16)v1.y; h[6] = (_Float16)v1.z; h[7] = (_Float16)v1.w;
    *(half8*)&w16[i8] = h;
}

// ---------------------------------------------------------------------------
// Kernel 1: gather+sum, GCN linear, support encoder, query gather.
// One block per batch row b, 512 threads. (Known wall: ~1.25 TB/s random.)
// ---------------------------------------------------------------------------
__global__ __launch_bounds__(512) void k_support(
    const int* __restrict__ relations, const int* __restrict__ entities,
    const int* __restrict__ query, const float* __restrict__ emb,
    const float* __restrict__ gcn_w, const float* __restrict__ gcn_b,
    const float* __restrict__ p1_w, const float* __restrict__ p1_b,
    const float* __restrict__ p2_w, const float* __restrict__ p2_b,
    const float* __restrict__ ln_a, const float* __restrict__ ln_b,
    float* __restrict__ sg, _Float16* __restrict__ sgH, _Float16* __restrict__ sgT,
    float* __restrict__ qb, _Float16* __restrict__ qbH)
{
    __shared__ int idxs[2 * KNB];
    __shared__ __align__(16) float part[16][132];
    __shared__ __align__(16) float S[2 * D];
    __shared__ __align__(16) float sup[D];
    __shared__ __align__(16) float hid[2 * D];
    __shared__ __align__(16) float zv[D];
    __shared__ float red2[2];

    const int b = blockIdx.x;
    const int t = threadIdx.x;

    if (t < KNB) idxs[t] = relations[b * KNB + t];
    else if (t < 2 * KNB) idxs[t] = entities[b * KNB + (t - KNB)];
    __syncthreads();

    {
        const int g = t >> 5, c4 = (t & 31) * 4;
        const int* mi = &idxs[(g >> 3) * KNB];
        float4 a4 = make_float4(0.f, 0.f, 0.f, 0.f);
        #pragma unroll 5
        for (int k = (g & 7); k < KNB; k += 8) {
            float4 v = *(const float4*)&emb[(size_t)mi[k] * D + c4];
            a4.x += v.x; a4.y += v.y; a4.z += v.z; a4.w += v.w;
        }
        *(float4*)&part[g][c4] = a4;
    }
    __syncthreads();
    if (t < 2 * D) {
        const int half = t >> 7, c = t & 127;
        float s = 0.f;
        #pragma unroll
        for (int j = 0; j < 8; ++j) s += part[half * 8 + j][c];
        S[t] = s;
    }
    __syncthreads();

    if (t < D) {
        const float4* w4 = (const float4*)(gcn_w + t * 2 * D);
        float dot = 0.f;
        #pragma unroll 8
        for (int f = 0; f < 2 * D / 4; ++f) {
            float4 w = w4[f];
            float4 s = *(const float4*)&S[f * 4];
            dot += w.x * s.x + w.y * s.y + w.z * s.z + w.w * s.w;
        }
        float v = (dot + 200.f * gcn_b[t]) * (1.f / 1024.f);  // num_neighbors = B = 1024
        sup[t] = tanhf(v);
    }
    __syncthreads();

    if (t < 2 * D) {
        const float4* w4 = (const float4*)(p1_w + t * D);
        float dot = 0.f;
        #pragma unroll 8
        for (int f = 0; f < D / 4; ++f) {
            float4 w = w4[f];
            float4 s = *(const float4*)&sup[f * 4];
            dot += w.x * s.x + w.y * s.y + w.z * s.z + w.w * s.w;
        }
        float h = dot + p1_b[t];
        hid[t] = h > 0.f ? h : 0.f;
    }
    __syncthreads();

    if (t < D) {
        const float4* w4 = (const float4*)(p2_w + t * 2 * D);
        float dot = 0.f;
        #pragma unroll 8
        for (int f = 0; f < 2 * D / 4; ++f) {
            float4 w = w4[f];
            float4 s = *(const float4*)&hid[f * 4];
            dot += w.x * s.x + w.y * s.y + w.z * s.z + w.w * s.w;
        }
        zv[t] = dot + p2_b[t] + sup[t];
    }
    __syncthreads();

    if (t < 64) {
        float x0 = zv[t], x1 = zv[t + 64];
        float s = x0 + x1;
        for (int off = 32; off; off >>= 1) s += __shfl_down(s, off);
        float mu = __shfl(s, 0) * (1.f / 128.f);
        float d0 = x0 - mu, d1 = x1 - mu;
        float v = d0 * d0 + d1 * d1;
        for (int off = 32; off; off >>= 1) v += __shfl_down(v, off);
        v = __shfl(v, 0);
        if (t == 0) { red2[0] = mu; red2[1] = sqrtf(v * (1.f / 127.f)); }
    }
    __syncthreads();
    if (t < D) {
        float mu = red2[0], sigma = red2[1];
        float val = (zv[t] - mu) / (sigma + 1e-3f) * ln_a[t] + ln_b[t];
        sg[b * D + t] = val;
        sgH[b * D + t] = (_Float16)val;
        sgT[t * B_SZ + b] = (_Float16)val;
        float qv = emb[(size_t)query[b] * D + t];
        qb[b * D + t] = qv;
        qbH[b * D + t] = (_Float16)qv;
    }
}

// ---------------------------------------------------------------------------
// Kernel 2: FUSED recurrence. 64 blocks x 16 rows, 1024 threads (16 waves).
// __launch_bounds__(1024, 4): 16 waves/CU = 4 waves/EU -> 128-VGPR budget.
// (81 KB LDS already caps us at 1 block/CU, so the default 64-reg/8-wave
// target the compiler picks without the 2nd arg only buys scratch spill.)
// gq = q @ w_ih^T computed ONCE into 16 persistent VGPRs; per-step gates
// GEMM is K=256 over [h|r] from LDS. Per-thread persistent state:
// gqr[16] + creg[4] + bi[4] -> fits 128 with room for the transient acc.
// ---------------------------------------------------------------------------
__global__ __launch_bounds__(1024, 4) void k_lstm(
    const _Float16* __restrict__ qbH, const float* __restrict__ qb,
    const _Float16* __restrict__ sgH, const _Float16* __restrict__ sgT,
    const float* __restrict__ sg, const _Float16* __restrict__ w16,
    const float* __restrict__ b_ih, const float* __restrict__ b_hh,
    float* __restrict__ out)
{
    __shared__ _Float16 Ah[16 * AHW];      // [row][0:128]=q, [128:256]=h, [256:384]=r
    __shared__ _Float16 P[16 * PW];        // unnormalized exp, fp16
    __shared__ float qF[16][132];          // q f32 (pointwise residual)
    __shared__ float hF[16][132];          // h f32 (for cosine)
    __shared__ float rpar[2][16][132];     // r K-half partials
    __shared__ float pred[16][17];         // [wave][row] partial max / partial sum
    __shared__ float mrow[16];
    __shared__ float sinv[16];

    const int t = threadIdx.x;
    const int w = t >> 6, lane = t & 63;
    const int m = lane & 15, quad = lane >> 4;
    const int b0 = blockIdx.x * 16;
    const int u = w * 16 + m;              // unit 0..255

    // ---- prologue: stage q (f16 into Ah[:,0:128], f32 into qF)
    if (t < 256) {
        const int row = t >> 4, c = (t & 15) * 8;
        *(half8*)&Ah[row * AHW + c] = *(const half8*)&qbH[(b0 + row) * D + c];
    }
    if (t < 512) {
        const int row = t >> 5, c = (t & 31) * 4;
        *(float4*)&qF[row][c] = *(const float4*)&qb[(b0 + row) * D + c];
    }
    float bi[4];
    #pragma unroll
    for (int g = 0; g < 4; ++g) bi[g] = b_ih[g * 256 + u] + b_hh[g * 256 + u];
    __syncthreads();

    // ---- gq = q @ w_ih^T, persistent in registers across all steps
    floatx4 gqr[4];
    #pragma unroll
    for (int g = 0; g < 4; ++g)
        #pragma unroll
        for (int z = 0; z < 4; ++z) gqr[g][z] = 0.f;
    #pragma unroll
    for (int ks = 0; ks < 4; ++ks) {
        half8 a = *(const half8*)&Ah[m * AHW + ks * 32 + quad * 8];
        #pragma unroll
        for (int g = 0; g < 4; ++g) {
            half8 bf = *(const half8*)&w16[(size_t)(g * 256 + u) * D + ks * 32 + quad * 8];
            gqr[g] = __builtin_amdgcn_mfma_f32_16x16x32_f16(a, bf, gqr[g], 0, 0, 0);
        }
    }

    // ---- step 0 pointwise (c = 0, h_r = 0)
    float creg[4];
    #pragma unroll
    for (int rr = 0; rr < 4; ++rr) {
        float gi = gqr[0][rr] + bi[0];
        float gg = gqr[2][rr] + bi[2];
        float go = gqr[3][rr] + bi[3];
        float cn = sigmoid_f(gi) * tanh_fast(gg);
        creg[rr] = cn;
        if (w < 8) {
            const int row = quad * 4 + rr;
            float ho = qF[row][u] + sigmoid_f(go) * tanh_fast(cn);
            Ah[row * AHW + 128 + u] = (_Float16)ho;
            hF[row][u] = ho;
        }
    }
    __syncthreads();

    #pragma unroll 1
    for (int s = 0; s < 3; ++s) {
        // ---- scores: wave w -> j-tiles 4w..4w+3 (h lives at Ah[:,128:256])
        floatx4 a2[4];
        #pragma unroll
        for (int i = 0; i < 4; ++i)
            #pragma unroll
            for (int z = 0; z < 4; ++z) a2[i][z] = 0.f;
        #pragma unroll
        for (int ks = 0; ks < 4; ++ks) {
            half8 a = *(const half8*)&Ah[m * AHW + 128 + ks * 32 + quad * 8];
            #pragma unroll
            for (int i = 0; i < 4; ++i) {
                const int j0 = (w * 4 + i) * 16;
                half8 bf = *(const half8*)&sgH[(j0 + m) * D + ks * 32 + quad * 8];
                a2[i] = __builtin_amdgcn_mfma_f32_16x16x32_f16(a, bf, a2[i], 0, 0, 0);
            }
        }

        // ---- softmax (register partials + two small LDS reductions)
        float mloc[4];
        #pragma unroll
        for (int rr = 0; rr < 4; ++rr)
            mloc[rr] = fmaxf(fmaxf(a2[0][rr], a2[1][rr]), fmaxf(a2[2][rr], a2[3][rr]));
        #pragma unroll
        for (int off = 1; off <= 8; off <<= 1)
            #pragma unroll
            for (int rr = 0; rr < 4; ++rr)
                mloc[rr] = fmaxf(mloc[rr], __shfl_xor(mloc[rr], off));
        if (m == 0) {
            #pragma unroll
            for (int rr = 0; rr < 4; ++rr) pred[w][quad * 4 + rr] = mloc[rr];
        }
        __syncthreads();
        if (t < 16) {
            float mm = -1e30f;
            #pragma unroll
            for (int ww = 0; ww < 16; ++ww) mm = fmaxf(mm, pred[ww][t]);
            mrow[t] = mm;
        }
        __syncthreads();

        float sloc[4] = {0.f, 0.f, 0.f, 0.f};
        #pragma unroll
        for (int i = 0; i < 4; ++i) {
            const int col = (w * 4 + i) * 16 + m;
            #pragma unroll
            for (int rr = 0; rr < 4; ++rr) {
                const int row = quad * 4 + rr;
                float e = __expf(a2[i][rr] - mrow[row]);
                P[row * PW + col] = (_Float16)e;
                sloc[rr] += e;
            }
        }
        #pragma unroll
        for (int off = 1; off <= 8; off <<= 1)
            #pragma unroll
            for (int rr = 0; rr < 4; ++rr)
                sloc[rr] += __shfl_xor(sloc[rr], off);
        if (m == 0) {
            #pragma unroll
            for (int rr = 0; rr < 4; ++rr) pred[w][quad * 4 + rr] = sloc[rr];
        }
        __syncthreads();
        if (t < 16) {
            float ss = 0.f;
            #pragma unroll
            for (int ww = 0; ww < 16; ++ww) ss += pred[ww][t];
            sinv[t] = 1.f / ss;
        }

        // ---- r partials: wave -> (n-tile = w&7, K-half = w>>3)
        //      two independent MFMA chains (8 deep each) instead of one 16-deep
        {
            const int nt = w & 7, kh = w >> 3;
            floatx4 a3a, a3b;
            #pragma unroll
            for (int z = 0; z < 4; ++z) { a3a[z] = 0.f; a3b[z] = 0.f; }
            #pragma unroll
            for (int ks = 0; ks < 8; ++ks) {
                const int k0 = kh * 16 + ks * 2;
                half8 aa = *(const half8*)&P[m * PW + k0 * 32 + quad * 8];
                half8 ba = *(const half8*)&sgT[(size_t)(nt * 16 + m) * B_SZ + k0 * 32 + quad * 8];
                a3a = __builtin_amdgcn_mfma_f32_16x16x32_f16(aa, ba, a3a, 0, 0, 0);
                half8 ab = *(const half8*)&P[m * PW + (k0 + 1) * 32 + quad * 8];
                half8 bb = *(const half8*)&sgT[(size_t)(nt * 16 + m) * B_SZ + (k0 + 1) * 32 + quad * 8];
                a3b = __builtin_amdgcn_mfma_f32_16x16x32_f16(ab, bb, a3b, 0, 0, 0);
            }
            #pragma unroll
            for (int rr = 0; rr < 4; ++rr)
                rpar[kh][quad * 4 + rr][nt * 16 + m] = a3a[rr] + a3b[rr];
        }
        __syncthreads();

        // ---- combine + scale -> r fp16 into Ah[:,256:384]
        #pragma unroll
        for (int half2 = 0; half2 < 2; ++half2) {
            const int e = t + half2 * 1024;
            const int row = e >> 7, dd = e & 127;
            float v = (rpar[0][row][dd] + rpar[1][row][dd]) * sinv[row];
            Ah[row * AHW + 256 + dd] = (_Float16)v;
        }
        __syncthreads();

        // ---- gates: acc = gq + [h|r] @ w_hh^T (K = 256)
        floatx4 acc[4];
        #pragma unroll
        for (int g = 0; g < 4; ++g) acc[g] = gqr[g];
        #pragma unroll
        for (int ks = 0; ks < 8; ++ks) {
            half8 a = *(const half8*)&Ah[m * AHW + 128 + ks * 32 + quad * 8];
            #pragma unroll
            for (int g = 0; g < 4; ++g) {
                half8 bf = *(const half8*)&w16[131072 + (size_t)(g * 256 + u) * 256 + ks * 32 + quad * 8];
                acc[g] = __builtin_amdgcn_mfma_f32_16x16x32_f16(a, bf, acc[g], 0, 0, 0);
            }
        }
        __syncthreads();   // all Ah reads done before h is overwritten

        // ---- pointwise
        #pragma unroll
        for (int rr = 0; rr < 4; ++rr) {
            float gi = acc[0][rr] + bi[0];
            float gf = acc[1][rr] + bi[1];
            float gg = acc[2][rr] + bi[2];
            float go = acc[3][rr] + bi[3];
            float cn = sigmoid_f(gf) * creg[rr] + sigmoid_f(gi) * tanh_fast(gg);
            creg[rr] = cn;
            if (w < 8) {
                const int row = quad * 4 + rr;
                float ho = qF[row][u] + sigmoid_f(go) * tanh_fast(cn);
                Ah[row * AHW + 128 + u] = (_Float16)ho;
                hF[row][u] = ho;
            }
        }
        __syncthreads();
    }

    // ---- cosine: wave w -> row w
    {
        const int row = w;
        float a0 = hF[row][lane], a1 = hF[row][lane + 64];
        float s0 = sg[(b0 + row) * D + lane], s1 = sg[(b0 + row) * D + lane + 64];
        float cr = a0 * s0 + a1 * s1;
        float n1 = a0 * a0 + a1 * a1;
        float n2 = s0 * s0 + s1 * s1;
        for (int off = 32; off; off >>= 1) {
            cr += __shfl_down(cr, off);
            n1 += __shfl_down(n1, off);
            n2 += __shfl_down(n2, off);
        }
        if (lane == 0) out[b0 + row] = cr / sqrtf(n1 * n2);
    }
}

// ---------------------------------------------------------------------------
extern "C" void kernel_launch(void* const* d_in, const int* in_sizes, int n_in,
                              void* d_out, int out_size, void* d_ws, size_t ws_size,
                              hipStream_t stream)
{
    const int*   relations = (const int*)d_in[0];
    const int*   entities  = (const int*)d_in[1];
    const int*   query     = (const int*)d_in[2];
    const float* emb       = (const float*)d_in[3];
    const float* gcn_w     = (const float*)d_in[4];
    const float* gcn_b     = (const float*)d_in[5];
    const float* p1_w      = (const float*)d_in[6];
    const float* p1_b      = (const float*)d_in[7];
    const float* p2_w      = (const float*)d_in[8];
    const float* p2_b      = (const float*)d_in[9];
    const float* ln_a      = (const float*)d_in[10];
    const float* ln_b      = (const float*)d_in[11];
    const float* w_ih      = (const float*)d_in[12];
    const float* w_hh      = (const float*)d_in[13];
    const float* b_ih      = (const float*)d_in[14];
    const float* b_hh      = (const float*)d_in[15];

    // Workspace layout (float-slot offsets)
    float* ws = (float*)d_ws;
    float*     sg   = ws;                          // 131072
    float*     qb   = ws + 131072;                 // 131072
    _Float16*  sgH  = (_Float16*)(ws + 262144);    // 65536 float slots
    _Float16*  sgT  = (_Float16*)(ws + 327680);
    _Float16*  qbH  = (_Float16*)(ws + 393216);
    _Float16*  w16  = (_Float16*)(ws + 458752);    // 196608 float slots
    // end: 655360 floats = 2.6 MB

    k_cvtw<<<dim3(192), dim3(256), 0, stream>>>(w_ih, w_hh, w16);
    k_support<<<dim3(B_SZ), dim3(512), 0, stream>>>(
        relations, entities, query, emb, gcn_w, gcn_b,
        p1_w, p1_b, p2_w, p2_b, ln_a, ln_b, sg, sgH, sgT, qb, qbH);
    k_lstm<<<dim3(64), dim3(1024), 0, stream>>>(
        qbH, qb, sgH, sgT, sg, w16, b_ih, b_hh, (float*)d_out);
}

// Round 4
// 334.575 us; speedup vs baseline: 1.1651x; 1.1180x over previous
//
#include <hip/hip_runtime.h>
#include <math.h>

#define D 128
#define B_SZ 1024
#define KNB 200
#define AHW 392   // [q|h|r] LDS stride (halves): 196 dw, %32=4 -> cheap 2-way pairs
#define PW 1048   // P LDS stride (halves)

typedef _Float16 half8 __attribute__((ext_vector_type(8)));
typedef float floatx4 __attribute__((ext_vector_type(4)));

__device__ __forceinline__ float sigmoid_f(float x) { return 1.f / (1.f + __expf(-x)); }
__device__ __forceinline__ float tanh_fast(float x) { return 1.f - 2.f / (__expf(2.f * x) + 1.f); }

// ---------------------------------------------------------------------------
// Kernel 0: one-time fp16 LSTM weights (split layout):
// w16[0:131072] = w_ih [1024][128]; w16[131072:] = w_hh [1024][256].
// ---------------------------------------------------------------------------
__global__ __launch_bounds__(256) void k_cvtw(
    const float* __restrict__ w_ih, const float* __restrict__ w_hh,
    _Float16* __restrict__ w16)
{
    const int i8 = (blockIdx.x * 256 + threadIdx.x) * 8;
    const float* src = (i8 < 131072) ? (w_ih + i8) : (w_hh + (i8 - 131072));
    float4 v0 = *(const float4*)src;
    float4 v1 = *(const float4*)(src + 4);
    half8 h;
    h[0] = (_Float16)v0.x; h[1] = (_Float16)v0.y; h[2] = (_Float16)v0.z; h[3] = (_Float16)v0.w;
    h[4] = (_Float16)v1.x; h[5] = (_Float16)v1.y; h[6] = (_Float16)v1.z; h[7] = (_Float16)v1.w;
    *(half8*)&w16[i8] = h;
}

// ---------------------------------------------------------------------------
// Kernel 1: gather+sum, GCN linear, support encoder, query gather.
// One block per batch row b, 512 threads. (Known wall: ~1.25 TB/s random.)
// ---------------------------------------------------------------------------
__global__ __launch_bounds__(512) void k_support(
    const int* __restrict__ relations, const int* __restrict__ entities,
    const int* __restrict__ query, const float* __restrict__ emb,
    const float* __restrict__ gcn_w, const float* __restrict__ gcn_b,
    const float* __restrict__ p1_w, const float* __restrict__ p1_b,
    const float* __restrict__ p2_w, const float* __restrict__ p2_b,
    const float* __restrict__ ln_a, const float* __restrict__ ln_b,
    float* __restrict__ sg, _Float16* __restrict__ sgH, _Float16* __restrict__ sgT,
    float* __restrict__ qb, _Float16* __restrict__ qbH)
{
    __shared__ int idxs[2 * KNB];
    __shared__ __align__(16) float part[16][132];
    __shared__ __align__(16) float S[2 * D];
    __shared__ __align__(16) float sup[D];
    __shared__ __align__(16) float hid[2 * D];
    __shared__ __align__(16) float zv[D];
    __shared__ float red2[2];

    const int b = blockIdx.x;
    const int t = threadIdx.x;

    if (t < KNB) idxs[t] = relations[b * KNB + t];
    else if (t < 2 * KNB) idxs[t] = entities[b * KNB + (t - KNB)];
    __syncthreads();

    {
        const int g = t >> 5, c4 = (t & 31) * 4;
        const int* mi = &idxs[(g >> 3) * KNB];
        float4 a4 = make_float4(0.f, 0.f, 0.f, 0.f);
        #pragma unroll 5
        for (int k = (g & 7); k < KNB; k += 8) {
            float4 v = *(const float4*)&emb[(size_t)mi[k] * D + c4];
            a4.x += v.x; a4.y += v.y; a4.z += v.z; a4.w += v.w;
        }
        *(float4*)&part[g][c4] = a4;
    }
    __syncthreads();
    if (t < 2 * D) {
        const int half = t >> 7, c = t & 127;
        float s = 0.f;
        #pragma unroll
        for (int j = 0; j < 8; ++j) s += part[half * 8 + j][c];
        S[t] = s;
    }
    __syncthreads();

    if (t < D) {
        const float4* w4 = (const float4*)(gcn_w + t * 2 * D);
        float dot = 0.f;
        #pragma unroll 8
        for (int f = 0; f < 2 * D / 4; ++f) {
            float4 w = w4[f];
            float4 s = *(const float4*)&S[f * 4];
            dot += w.x * s.x + w.y * s.y + w.z * s.z + w.w * s.w;
        }
        float v = (dot + 200.f * gcn_b[t]) * (1.f / 1024.f);  // num_neighbors = B = 1024
        sup[t] = tanhf(v);
    }
    __syncthreads();

    if (t < 2 * D) {
        const float4* w4 = (const float4*)(p1_w + t * D);
        float dot = 0.f;
        #pragma unroll 8
        for (int f = 0; f < D / 4; ++f) {
            float4 w = w4[f];
            float4 s = *(const float4*)&sup[f * 4];
            dot += w.x * s.x + w.y * s.y + w.z * s.z + w.w * s.w;
        }
        float h = dot + p1_b[t];
        hid[t] = h > 0.f ? h : 0.f;
    }
    __syncthreads();

    if (t < D) {
        const float4* w4 = (const float4*)(p2_w + t * 2 * D);
        float dot = 0.f;
        #pragma unroll 8
        for (int f = 0; f < 2 * D / 4; ++f) {
            float4 w = w4[f];
            float4 s = *(const float4*)&hid[f * 4];
            dot += w.x * s.x + w.y * s.y + w.z * s.z + w.w * s.w;
        }
        zv[t] = dot + p2_b[t] + sup[t];
    }
    __syncthreads();

    if (t < 64) {
        float x0 = zv[t], x1 = zv[t + 64];
        float s = x0 + x1;
        for (int off = 32; off; off >>= 1) s += __shfl_down(s, off);
        float mu = __shfl(s, 0) * (1.f / 128.f);
        float d0 = x0 - mu, d1 = x1 - mu;
        float v = d0 * d0 + d1 * d1;
        for (int off = 32; off; off >>= 1) v += __shfl_down(v, off);
        v = __shfl(v, 0);
        if (t == 0) { red2[0] = mu; red2[1] = sqrtf(v * (1.f / 127.f)); }
    }
    __syncthreads();
    if (t < D) {
        float mu = red2[0], sigma = red2[1];
        float val = (zv[t] - mu) / (sigma + 1e-3f) * ln_a[t] + ln_b[t];
        sg[b * D + t] = val;
        sgH[b * D + t] = (_Float16)val;
        sgT[t * B_SZ + b] = (_Float16)val;
        float qv = emb[(size_t)query[b] * D + t];
        qb[b * D + t] = qv;
        qbH[b * D + t] = (_Float16)qv;
    }
}

// ---------------------------------------------------------------------------
// Kernel 2: FUSED recurrence. 64 blocks x 16 rows, 1024 threads (16 waves).
// amdgpu_waves_per_eu(4,4): 81 KB LDS caps us at 1 block/CU = 4 waves/EU, so
// tell the allocator that IS the occupancy -> 128-VGPR budget (the bare
// launch_bounds min-arg only bounds regs above, it doesn't move the
// allocator's 8-wave default target -> it chose 64 and spilled).
// All global-streaming GEMM ks-loops are `#pragma unroll 1` so the compiler
// cannot hoist 32 half8 loads (=128 VGPRs of destinations) at once; latency
// is hidden by 16 waves of TLP instead.
// ---------------------------------------------------------------------------
__global__ __launch_bounds__(1024)
__attribute__((amdgpu_waves_per_eu(4, 4)))
void k_lstm(
    const _Float16* __restrict__ qbH, const float* __restrict__ qb,
    const _Float16* __restrict__ sgH, const _Float16* __restrict__ sgT,
    const float* __restrict__ sg, const _Float16* __restrict__ w16,
    const float* __restrict__ b_ih, const float* __restrict__ b_hh,
    float* __restrict__ out)
{
    __shared__ _Float16 Ah[16 * AHW];      // [row][0:128]=q, [128:256]=h, [256:384]=r
    __shared__ _Float16 P[16 * PW];        // unnormalized exp, fp16
    __shared__ float qF[16][132];          // q f32 (pointwise residual)
    __shared__ float hF[16][132];          // h f32 (for cosine)
    __shared__ float rpar[2][16][132];     // r K-half partials
    __shared__ float pred[16][17];         // [wave][row] partial max / partial sum
    __shared__ float mrow[16];
    __shared__ float sinv[16];

    const int t = threadIdx.x;
    const int w = t >> 6, lane = t & 63;
    const int m = lane & 15, quad = lane >> 4;
    const int b0 = blockIdx.x * 16;
    const int u = w * 16 + m;              // unit 0..255

    // ---- prologue: stage q (f16 into Ah[:,0:128], f32 into qF)
    if (t < 256) {
        const int row = t >> 4, c = (t & 15) * 8;
        *(half8*)&Ah[row * AHW + c] = *(const half8*)&qbH[(b0 + row) * D + c];
    }
    if (t < 512) {
        const int row = t >> 5, c = (t & 31) * 4;
        *(float4*)&qF[row][c] = *(const float4*)&qb[(b0 + row) * D + c];
    }
    float bi[4];
    #pragma unroll
    for (int g = 0; g < 4; ++g) bi[g] = b_ih[g * 256 + u] + b_hh[g * 256 + u];
    __syncthreads();

    // ---- gq = q @ w_ih^T, persistent in registers across all steps
    floatx4 gqr[4];
    #pragma unroll
    for (int g = 0; g < 4; ++g)
        #pragma unroll
        for (int z = 0; z < 4; ++z) gqr[g][z] = 0.f;
    #pragma unroll 1
    for (int ks = 0; ks < 4; ++ks) {
        half8 a = *(const half8*)&Ah[m * AHW + ks * 32 + quad * 8];
        #pragma unroll
        for (int g = 0; g < 4; ++g) {
            half8 bf = *(const half8*)&w16[(size_t)(g * 256 + u) * D + ks * 32 + quad * 8];
            gqr[g] = __builtin_amdgcn_mfma_f32_16x16x32_f16(a, bf, gqr[g], 0, 0, 0);
        }
    }

    // ---- step 0 pointwise (c = 0, h_r = 0)
    float creg[4];
    #pragma unroll
    for (int rr = 0; rr < 4; ++rr) {
        float gi = gqr[0][rr] + bi[0];
        float gg = gqr[2][rr] + bi[2];
        float go = gqr[3][rr] + bi[3];
        float cn = sigmoid_f(gi) * tanh_fast(gg);
        creg[rr] = cn;
        if (w < 8) {
            const int row = quad * 4 + rr;
            float ho = qF[row][u] + sigmoid_f(go) * tanh_fast(cn);
            Ah[row * AHW + 128 + u] = (_Float16)ho;
            hF[row][u] = ho;
        }
    }
    __syncthreads();

    #pragma unroll 1
    for (int s = 0; s < 3; ++s) {
        // ---- scores: wave w -> j-tiles 4w..4w+3 (h lives at Ah[:,128:256])
        floatx4 a2[4];
        #pragma unroll
        for (int i = 0; i < 4; ++i)
            #pragma unroll
            for (int z = 0; z < 4; ++z) a2[i][z] = 0.f;
        #pragma unroll 1
        for (int ks = 0; ks < 4; ++ks) {
            half8 a = *(const half8*)&Ah[m * AHW + 128 + ks * 32 + quad * 8];
            #pragma unroll
            for (int i = 0; i < 4; ++i) {
                const int j0 = (w * 4 + i) * 16;
                half8 bf = *(const half8*)&sgH[(size_t)(j0 + m) * D + ks * 32 + quad * 8];
                a2[i] = __builtin_amdgcn_mfma_f32_16x16x32_f16(a, bf, a2[i], 0, 0, 0);
            }
        }

        // ---- softmax (register partials + two small LDS reductions)
        float mloc[4];
        #pragma unroll
        for (int rr = 0; rr < 4; ++rr)
            mloc[rr] = fmaxf(fmaxf(a2[0][rr], a2[1][rr]), fmaxf(a2[2][rr], a2[3][rr]));
        #pragma unroll
        for (int off = 1; off <= 8; off <<= 1)
            #pragma unroll
            for (int rr = 0; rr < 4; ++rr)
                mloc[rr] = fmaxf(mloc[rr], __shfl_xor(mloc[rr], off));
        if (m == 0) {
            #pragma unroll
            for (int rr = 0; rr < 4; ++rr) pred[w][quad * 4 + rr] = mloc[rr];
        }
        __syncthreads();
        if (t < 16) {
            float mm = -1e30f;
            #pragma unroll
            for (int ww = 0; ww < 16; ++ww) mm = fmaxf(mm, pred[ww][t]);
            mrow[t] = mm;
        }
        __syncthreads();

        float sloc[4] = {0.f, 0.f, 0.f, 0.f};
        #pragma unroll
        for (int i = 0; i < 4; ++i) {
            const int col = (w * 4 + i) * 16 + m;
            #pragma unroll
            for (int rr = 0; rr < 4; ++rr) {
                const int row = quad * 4 + rr;
                float e = __expf(a2[i][rr] - mrow[row]);
                P[row * PW + col] = (_Float16)e;
                sloc[rr] += e;
            }
        }
        #pragma unroll
        for (int off = 1; off <= 8; off <<= 1)
            #pragma unroll
            for (int rr = 0; rr < 4; ++rr)
                sloc[rr] += __shfl_xor(sloc[rr], off);
        if (m == 0) {
            #pragma unroll
            for (int rr = 0; rr < 4; ++rr) pred[w][quad * 4 + rr] = sloc[rr];
        }
        __syncthreads();
        if (t < 16) {
            float ss = 0.f;
            #pragma unroll
            for (int ww = 0; ww < 16; ++ww) ss += pred[ww][t];
            sinv[t] = 1.f / ss;
        }

        // ---- r partials: wave -> (n-tile = w&7, K-half = w>>3), single chain
        {
            const int nt = w & 7, kh = w >> 3;
            floatx4 a3;
            #pragma unroll
            for (int z = 0; z < 4; ++z) a3[z] = 0.f;
            #pragma unroll 1
            for (int ks = 0; ks < 16; ++ks) {
                const int kk = kh * 16 + ks;
                half8 a = *(const half8*)&P[m * PW + kk * 32 + quad * 8];
                half8 bf = *(const half8*)&sgT[(size_t)(nt * 16 + m) * B_SZ + kk * 32 + quad * 8];
                a3 = __builtin_amdgcn_mfma_f32_16x16x32_f16(a, bf, a3, 0, 0, 0);
            }
            #pragma unroll
            for (int rr = 0; rr < 4; ++rr)
                rpar[kh][quad * 4 + rr][nt * 16 + m] = a3[rr];
        }
        __syncthreads();

        // ---- combine + scale -> r fp16 into Ah[:,256:384]
        #pragma unroll
        for (int half2 = 0; half2 < 2; ++half2) {
            const int e = t + half2 * 1024;
            const int row = e >> 7, dd = e & 127;
            float v = (rpar[0][row][dd] + rpar[1][row][dd]) * sinv[row];
            Ah[row * AHW + 256 + dd] = (_Float16)v;
        }
        __syncthreads();

        // ---- gates: acc = gq + [h|r] @ w_hh^T (K = 256)
        floatx4 acc[4];
        #pragma unroll
        for (int g = 0; g < 4; ++g) acc[g] = gqr[g];
        #pragma unroll 1
        for (int ks = 0; ks < 8; ++ks) {
            half8 a = *(const half8*)&Ah[m * AHW + 128 + ks * 32 + quad * 8];
            #pragma unroll
            for (int g = 0; g < 4; ++g) {
                half8 bf = *(const half8*)&w16[131072 + (size_t)(g * 256 + u) * 256 + ks * 32 + quad * 8];
                acc[g] = __builtin_amdgcn_mfma_f32_16x16x32_f16(a, bf, acc[g], 0, 0, 0);
            }
        }
        __syncthreads();   // all Ah reads done before h is overwritten

        // ---- pointwise
        #pragma unroll
        for (int rr = 0; rr < 4; ++rr) {
            float gi = acc[0][rr] + bi[0];
            float gf = acc[1][rr] + bi[1];
            float gg = acc[2][rr] + bi[2];
            float go = acc[3][rr] + bi[3];
            float cn = sigmoid_f(gf) * creg[rr] + sigmoid_f(gi) * tanh_fast(gg);
            creg[rr] = cn;
            if (w < 8) {
                const int row = quad * 4 + rr;
                float ho = qF[row][u] + sigmoid_f(go) * tanh_fast(cn);
                Ah[row * AHW + 128 + u] = (_Float16)ho;
                hF[row][u] = ho;
            }
        }
        __syncthreads();
    }

    // ---- cosine: wave w -> row w
    {
        const int row = w;
        float a0 = hF[row][lane], a1 = hF[row][lane + 64];
        float s0 = sg[(b0 + row) * D + lane], s1 = sg[(b0 + row) * D + lane + 64];
        float cr = a0 * s0 + a1 * s1;
        float n1 = a0 * a0 + a1 * a1;
        float n2 = s0 * s0 + s1 * s1;
        for (int off = 32; off; off >>= 1) {
            cr += __shfl_down(cr, off);
            n1 += __shfl_down(n1, off);
            n2 += __shfl_down(n2, off);
        }
        if (lane == 0) out[b0 + row] = cr / sqrtf(n1 * n2);
    }
}

// ---------------------------------------------------------------------------
extern "C" void kernel_launch(void* const* d_in, const int* in_sizes, int n_in,
                              void* d_out, int out_size, void* d_ws, size_t ws_size,
                              hipStream_t stream)
{
    const int*   relations = (const int*)d_in[0];
    const int*   entities  = (const int*)d_in[1];
    const int*   query     = (const int*)d_in[2];
    const float* emb       = (const float*)d_in[3];
    const float* gcn_w     = (const float*)d_in[4];
    const float* gcn_b     = (const float*)d_in[5];
    const float* p1_w      = (const float*)d_in[6];
    const float* p1_b      = (const float*)d_in[7];
    const float* p2_w      = (const float*)d_in[8];
    const float* p2_b      = (const float*)d_in[9];
    const float* ln_a      = (const float*)d_in[10];
    const float* ln_b      = (const float*)d_in[11];
    const float* w_ih      = (const float*)d_in[12];
    const float* w_hh      = (const float*)d_in[13];
    const float* b_ih      = (const float*)d_in[14];
    const float* b_hh      = (const float*)d_in[15];

    // Workspace layout (float-slot offsets)
    float* ws = (float*)d_ws;
    float*     sg   = ws;                          // 131072
    float*     qb   = ws + 131072;                 // 131072
    _Float16*  sgH  = (_Float16*)(ws + 262144);    // 65536 float slots
    _Float16*  sgT  = (_Float16*)(ws + 327680);
    _Float16*  qbH  = (_Float16*)(ws + 393216);
    _Float16*  w16  = (_Float16*)(ws + 458752);    // 196608 float slots
    // end: 655360 floats = 2.6 MB

    k_cvtw<<<dim3(192), dim3(256), 0, stream>>>(w_ih, w_hh, w16);
    k_support<<<dim3(B_SZ), dim3(512), 0, stream>>>(
        relations, entities, query, emb, gcn_w, gcn_b,
        p1_w, p1_b, p2_w, p2_b, ln_a, ln_b, sg, sgH, sgT, qb, qbH);
    k_lstm<<<dim3(64), dim3(1024), 0, stream>>>(
        qbH, qb, sgH, sgT, sg, w16, b_ih, b_hh, (float*)d_out);
}